// Round 1
// 165.436 us; speedup vs baseline: 4.6468x; 4.6468x over previous
//
#include <hip/hip_runtime.h>

typedef __bf16 bf16_t;
typedef __bf16 bf16x2 __attribute__((ext_vector_type(2)));
typedef __bf16 bf16x8 __attribute__((ext_vector_type(8)));
typedef float f32x4 __attribute__((ext_vector_type(4)));

#define MFMA_BF16(a, b, c) __builtin_amdgcn_mfma_f32_16x16x32_bf16((a), (b), (c), 0, 0, 0)

static constexpr int Bn = 4096;
static constexpr int Dn = 1024;
static constexpr int Rn = 256;
static constexpr int BT = 16;
static constexpr float DTv = 0.01f;
static constexpr float HDT = 0.005f;

// ---- Pack U [D=1024, R=256] fp32 -> bf16 B-operand fragment layout ----
// Upk[((ct*32 + kb)*64 + lane)*8 + j] = U[kb*32 + (lane>>4)*8 + j][ct*16 + (lane&15)]
__global__ void pack_u_kernel(const float* __restrict__ U, bf16_t* __restrict__ Upk) {
  int t = blockIdx.x * blockDim.x + threadIdx.x;  // 32768 threads
  int l = t & 63;
  int f = t >> 6;
  int kb = f & 31;
  int ct = f >> 5;
  int row0 = kb * 32 + (l >> 4) * 8;
  int col = ct * 16 + (l & 15);
  bf16x8 v;
#pragma unroll
  for (int j = 0; j < 8; ++j) v[j] = (bf16_t)U[(size_t)(row0 + j) * Rn + col];
  ((bf16x8*)Upk)[t] = v;
}

// ---- Pack W [R=256, D=1024] fp32 -> bf16 B-operand fragment layout ----
// Wpk[((ct*8 + kb)*64 + lane)*8 + j] = W[kb*32 + (lane>>4)*8 + j][ct*16 + (lane&15)]
__global__ void pack_w_kernel(const float* __restrict__ W, bf16_t* __restrict__ Wpk) {
  int t = blockIdx.x * blockDim.x + threadIdx.x;  // 32768 threads
  int l = t & 63;
  int f = t >> 6;
  int kb = f & 7;
  int ct = f >> 3;
  int row0 = kb * 32 + (l >> 4) * 8;
  int col = ct * 16 + (l & 15);
  bf16x8 v;
#pragma unroll
  for (int j = 0; j < 8; ++j) v[j] = (bf16_t)W[(size_t)(row0 + j) * Dn + col];
  ((bf16x8*)Wpk)[t] = v;
}

// ---- WU = W @ U  [256 x 256], written directly in packed B-fragment layout ----
// WUpk[((ct*8 + kb)*64 + lane)*8 + j] = WU[kb*32 + (lane>>4)*8 + j][ct*16 + (lane&15)]
// 16 blocks x 1024 threads; block m owns W rows m*16..m*16+15 (A-tile), wave wv owns ct=wv.
__global__ __launch_bounds__(1024)
void wu_mfma_kernel(const float* __restrict__ W, const bf16_t* __restrict__ Upk,
                    bf16_t* __restrict__ WUpk) {
  __shared__ __align__(16) bf16_t wbuf[16 * 1032];
  const int tid = (int)threadIdx.x;
  const int wv = tid >> 6;
  const int l = tid & 63;
  const int ln = l & 15;
  const int quad = l >> 4;
  const int m = (int)blockIdx.x;  // 16 blocks
  {
    int row = tid >> 6;
    int c0 = (tid & 63) * 16;
    const float* src = W + (size_t)(m * 16 + row) * Dn + c0;
    bf16_t* dst = wbuf + row * 1032 + c0;
#pragma unroll
    for (int j = 0; j < 16; ++j) dst[j] = (bf16_t)src[j];
  }
  __syncthreads();
  f32x4 acc = {0.f, 0.f, 0.f, 0.f};
  const bf16x8* up = (const bf16x8*)Upk + (size_t)wv * 32 * 64 + l;
  const bf16_t* arow = wbuf + ln * 1032 + quad * 8;
  bf16x8 ur[4];
#pragma unroll
  for (int p = 0; p < 4; ++p) ur[p] = up[p * 64];
#pragma unroll
  for (int kb = 0; kb < 32; ++kb) {
    const bf16x8 a = *(const bf16x8*)(arow + kb * 32);
    const bf16x8 b = ur[kb & 3];
    if (kb < 28) ur[kb & 3] = up[(kb + 4) * 64];
    acc = MFMA_BF16(a, b, acc);
  }
  // thread holds WU[rw][c] with rw = m*16 + quad*4 + r, c = wv*16 + ln; scatter to pack slots
#pragma unroll
  for (int r = 0; r < 4; ++r) {
    int rw = m * 16 + quad * 4 + r;
    int kb = rw >> 5;
    int sub = (rw >> 3) & 3;
    int j = rw & 7;
    size_t slot = ((size_t)(wv * 8 + kb) * 64 + sub * 16 + ln) * 8 + j;
    WUpk[slot] = (bf16_t)acc[r];
  }
}

// ---- Fused integrator, R-space loop ----
// Identity (exact in exact arithmetic, verified against the half-step recurrence):
//   hv_{h+1} = hv_h + hdt*(FU - T_h@WU),   FU = f@U, WU = W@U
//   v_out = v0 + s*dt*f - hdt*(S1@W),      S1 = sum_h T_h
//   x_out = x0 + s*dt*v0 + s^2*dt*hdt*f - dt*hdt*(S2@W),  S2 = sum_h c_h*T_h, c_h = s - ceil(h/2)
// U streamed ONCE (init: hx0/hv0/FU share fragments), W streamed ONCE (final: S1/S2 share),
// loop is LDS+register only. 256 blocks x 1024 threads, 1 block/CU.
__global__ __launch_bounds__(1024)
__attribute__((amdgpu_waves_per_eu(4, 4)))
void integrate_kernel(const float* __restrict__ x_in, const float* __restrict__ v_in,
                      const float* __restrict__ force,
                      const bf16_t* __restrict__ Upk, const bf16_t* __restrict__ Wpk,
                      const bf16_t* __restrict__ WUpk,
                      const int* __restrict__ steps_p, float* __restrict__ out) {
  // union LDS region: init abuf[3][16][520] (49920B) / loop tbf[16][264] / final sbuf[2][16][264]
  __shared__ __align__(16) char smem[49920];
  bf16_t* abuf = (bf16_t*)smem;
  bf16_t* tbf = (bf16_t*)smem;
  bf16_t* sbuf = (bf16_t*)smem;

  const int tid = (int)threadIdx.x;
  const int wv = tid >> 6;   // 0..15
  const int l = tid & 63;
  const int ln = l & 15;
  const int quad = l >> 4;
  const int s = steps_p[0];
  const int nhalf = 2 * s;
  const int row_base = (int)blockIdx.x * BT;

  float* out_x = out;
  float* out_v = out + (size_t)Bn * Dn;

  // Register state, C/D layout. Element (i,r): row row_base+quad*4+r, col (wv*4+i)*16+ln
  float xs[4][4], vs[4][4];  // ORIGINAL x0, v0 (never updated)
  bf16x2 fs2[4][2];

#pragma unroll
  for (int i = 0; i < 4; ++i) {
    const int col = (wv * 4 + i) * 16 + ln;
#pragma unroll
    for (int r = 0; r < 4; ++r) {
      const size_t g = (size_t)(row_base + quad * 4 + r) * Dn + col;
      xs[i][r] = x_in[g];
      vs[i][r] = v_in[g];
      fs2[i][r >> 1][r & 1] = (bf16_t)force[g];
    }
  }

  // ---- init: hx0 = x0@U, hv0 = v0@U, FU = f@U, one Upk pass in two K-halves ----
  f32x4 hx = {0.f, 0.f, 0.f, 0.f};
  f32x4 hv = {0.f, 0.f, 0.f, 0.f};
  f32x4 FU = {0.f, 0.f, 0.f, 0.f};
#pragma unroll
  for (int kh = 0; kh < 2; ++kh) {
    if ((wv >> 3) == kh) {  // waves 0-7 stage K-cols [0,512); waves 8-15 stage [512,1024)
#pragma unroll
      for (int i = 0; i < 4; ++i) {
        const int col = (wv * 4 + i) * 16 + ln - kh * 512;
#pragma unroll
        for (int r = 0; r < 4; ++r) {
          const int ro = (quad * 4 + r) * 520 + col;
          abuf[ro] = (bf16_t)xs[i][r];
          abuf[8320 + ro] = (bf16_t)vs[i][r];
          abuf[16640 + ro] = fs2[i][r >> 1][r & 1];
        }
      }
    }
    __syncthreads();
    const bf16x8* up = (const bf16x8*)Upk + ((size_t)wv * 32 + kh * 16) * 64 + l;
    const bf16_t* ax = abuf + ln * 520 + quad * 8;
    bf16x8 ur[8];
#pragma unroll
    for (int p = 0; p < 8; ++p) ur[p] = up[p * 64];
#pragma unroll
    for (int kb = 0; kb < 16; ++kb) {
      const bf16x8 b = ur[kb & 7];
      if (kb < 8) ur[kb & 7] = up[(kb + 8) * 64];
      const bf16x8 a0 = *(const bf16x8*)(ax + kb * 32);
      const bf16x8 a1 = *(const bf16x8*)(ax + 8320 + kb * 32);
      const bf16x8 a2 = *(const bf16x8*)(ax + 16640 + kb * 32);
      hx = MFMA_BF16(a0, b, hx);
      hv = MFMA_BF16(a1, b, hv);
      FU = MFMA_BF16(a2, b, FU);
    }
    __syncthreads();
  }

  // ---- WU fragments for ct = wv, register-resident for the whole loop (8 KB/wave) ----
  bf16x8 wu[8];
  {
    const bf16x8* wub = (const bf16x8*)WUpk + (size_t)wv * 8 * 64 + l;
#pragma unroll
    for (int kb = 0; kb < 8; ++kb) wu[kb] = wub[kb * 64];
  }

  // ---- R-space loop: zero global traffic ----
  f32x4 S1 = {0.f, 0.f, 0.f, 0.f};
  f32x4 S2 = {0.f, 0.f, 0.f, 0.f};
  for (int h = 0; h < nhalf; ++h) {
    if (h & 1) {
#pragma unroll
      for (int r = 0; r < 4; ++r) hx[r] += DTv * hv[r];
    }
    const float ch = (float)(s - ((h + 1) >> 1));
#pragma unroll
    for (int r = 0; r < 4; ++r) {
      float a = fminf(fmaxf(hx[r], -15.f), 15.f);
      const float e = __expf(2.f * a);
      const float gate = (e - 1.f) / (e + 1.f);
      const float t = gate * hv[r] * hv[r];
      S1[r] += t;
      S2[r] += ch * t;
      tbf[(quad * 4 + r) * 264 + wv * 16 + ln] = (bf16_t)t;
    }
    __syncthreads();
    f32x4 g = {0.f, 0.f, 0.f, 0.f};
    const bf16_t* trow = tbf + ln * 264 + quad * 8;
#pragma unroll
    for (int kb = 0; kb < 8; ++kb) {
      const bf16x8 a = *(const bf16x8*)(trow + kb * 32);
      g = MFMA_BF16(a, wu[kb], g);
    }
#pragma unroll
    for (int r = 0; r < 4; ++r) hv[r] += HDT * (FU[r] - g[r]);
    __syncthreads();
  }

  // ---- final: G1 = S1@W, G2 = S2@W, one Wpk pass (fragments shared by both A-tiles) ----
#pragma unroll
  for (int r = 0; r < 4; ++r) {
    const int ro = (quad * 4 + r) * 264 + wv * 16 + ln;
    sbuf[ro] = (bf16_t)S1[r];
    sbuf[4224 + ro] = (bf16_t)S2[r];
  }
  __syncthreads();
  f32x4 ac1[4], ac2[4];
#pragma unroll
  for (int i = 0; i < 4; ++i) {
    ac1[i] = (f32x4){0.f, 0.f, 0.f, 0.f};
    ac2[i] = (f32x4){0.f, 0.f, 0.f, 0.f};
  }
  {
    const bf16x8* wp = (const bf16x8*)Wpk + (size_t)(wv * 4) * 8 * 64 + l;
    const bf16_t* s1row = sbuf + ln * 264 + quad * 8;
    const bf16_t* s2row = s1row + 4224;
    bf16x8 wr[4];
#pragma unroll
    for (int i = 0; i < 4; ++i) wr[i] = wp[i * 8 * 64];
#pragma unroll
    for (int kb = 0; kb < 8; ++kb) {
      const bf16x8 a1 = *(const bf16x8*)(s1row + kb * 32);
      const bf16x8 a2 = *(const bf16x8*)(s2row + kb * 32);
#pragma unroll
      for (int i = 0; i < 4; ++i) {
        const bf16x8 b = wr[i];
        if (kb < 7) wr[i] = wp[i * 8 * 64 + (kb + 1) * 64];
        ac1[i] = MFMA_BF16(a1, b, ac1[i]);
        ac2[i] = MFMA_BF16(a2, b, ac2[i]);
      }
    }
  }

  // ---- epilogue: closed-form outputs ----
  const float sf = (float)s;
  const float c_vf = sf * DTv;              // s*dt
  const float c_xf = sf * sf * DTv * HDT;   // s^2*dt*hdt
#pragma unroll
  for (int i = 0; i < 4; ++i) {
    const int col = (wv * 4 + i) * 16 + ln;
#pragma unroll
    for (int r = 0; r < 4; ++r) {
      const size_t g = (size_t)(row_base + quad * 4 + r) * Dn + col;
      const float fv = (float)fs2[i][r >> 1][r & 1];
      out_v[g] = vs[i][r] + c_vf * fv - HDT * ac1[i][r];
      out_x[g] = xs[i][r] + c_vf * vs[i][r] + c_xf * fv - DTv * HDT * ac2[i][r];
    }
  }
}

extern "C" void kernel_launch(void* const* d_in, const int* in_sizes, int n_in,
                              void* d_out, int out_size, void* d_ws, size_t ws_size,
                              hipStream_t stream) {
  const float* x = (const float*)d_in[0];
  const float* v = (const float*)d_in[1];
  const float* force = (const float*)d_in[2];
  const float* U = (const float*)d_in[3];
  const float* W = (const float*)d_in[4];
  const int* steps = (const int*)d_in[5];

  bf16_t* Upk = (bf16_t*)d_ws;                                   // 512 KB
  bf16_t* Wpk = (bf16_t*)((char*)d_ws + 512 * 1024);             // 512 KB
  bf16_t* WUpk = (bf16_t*)((char*)d_ws + 1024 * 1024);           // 128 KB

  pack_u_kernel<<<128, 256, 0, stream>>>(U, Upk);
  pack_w_kernel<<<128, 256, 0, stream>>>(W, Wpk);
  wu_mfma_kernel<<<16, 1024, 0, stream>>>(W, Upk, WUpk);
  integrate_kernel<<<Bn / BT, 1024, 0, stream>>>(x, v, force, Upk, Wpk, WUpk, steps,
                                                 (float*)d_out);
}

// Round 2
// 159.861 us; speedup vs baseline: 4.8088x; 1.0349x over previous
//
#include <hip/hip_runtime.h>

typedef __bf16 bf16_t;
typedef __bf16 bf16x2 __attribute__((ext_vector_type(2)));
typedef __bf16 bf16x8 __attribute__((ext_vector_type(8)));
typedef float f32x4 __attribute__((ext_vector_type(4)));

#define MFMA_BF16(a, b, c) __builtin_amdgcn_mfma_f32_16x16x32_bf16((a), (b), (c), 0, 0, 0)

static constexpr int Bn = 4096;
static constexpr int Dn = 1024;
static constexpr int Rn = 256;
static constexpr int BT = 16;
static constexpr float DTv = 0.01f;
static constexpr float HDT = 0.005f;

// XOR-swizzle within a 1024-float row: flips bits [4:2] by bits [7:5]. Bijective,
// preserves 4-float (16B) contiguity, spreads stride-8-float access over 8 bank-slots.
__device__ __forceinline__ int swz(int col) { return col ^ (((col >> 5) & 7) << 2); }

// ---- Fused setup: pack U, pack W, compute WU=W@U — one launch, no cross-block deps ----
// blocks 0..31: pack U -> Upk; 32..63: pack W -> Wpk; 64..79: WU (reads RAW U, packs B-frags
// on the fly with a depth-8 prefetch ring).
// Upk[((ct*32+kb)*64+lane)*8+j] = U[kb*32+(lane>>4)*8+j][ct*16+(lane&15)]
// Wpk[((ct*8+kb)*64+lane)*8+j]  = W[kb*32+(lane>>4)*8+j][ct*16+(lane&15)]
// WUpk same layout as Wpk for WU[256x256].
__global__ __launch_bounds__(1024)
void setup_kernel(const float* __restrict__ U, const float* __restrict__ W,
                  bf16_t* __restrict__ Upk, bf16_t* __restrict__ Wpk,
                  bf16_t* __restrict__ WUpk) {
  __shared__ __align__(16) bf16_t wbuf[16 * 1032];
  const int tid = (int)threadIdx.x;
  const int b = (int)blockIdx.x;
  if (b < 32) {  // ---- pack U ----
    int t = b * 1024 + tid;
    int l = t & 63, f = t >> 6;
    int kb = f & 31, ct = f >> 5;
    int row0 = kb * 32 + (l >> 4) * 8, col = ct * 16 + (l & 15);
    bf16x8 v;
#pragma unroll
    for (int j = 0; j < 8; ++j) v[j] = (bf16_t)U[(size_t)(row0 + j) * Rn + col];
    ((bf16x8*)Upk)[t] = v;
  } else if (b < 64) {  // ---- pack W ----
    int t = (b - 32) * 1024 + tid;
    int l = t & 63, f = t >> 6;
    int kb = f & 7, ct = f >> 3;
    int row0 = kb * 32 + (l >> 4) * 8, col = ct * 16 + (l & 15);
    bf16x8 v;
#pragma unroll
    for (int j = 0; j < 8; ++j) v[j] = (bf16_t)W[(size_t)(row0 + j) * Dn + col];
    ((bf16x8*)Wpk)[t] = v;
  } else {  // ---- WU = W @ U, block m owns W rows m*16..+16 ----
    const int m = b - 64;
    const int wv = tid >> 6;
    const int l = tid & 63;
    const int ln = l & 15;
    const int quad = l >> 4;
    {
      int row = tid >> 6;
      int c0 = (tid & 63) * 16;
      const float* src = W + (size_t)(m * 16 + row) * Dn + c0;
      bf16_t* dst = wbuf + row * 1032 + c0;
#pragma unroll
      for (int j = 0; j < 16; ++j) dst[j] = (bf16_t)src[j];
    }
    __syncthreads();
    const int ucol = wv * 16 + ln;
    float uf[8][8];  // depth-8 ring, fully unrolled -> all indices compile-time
#pragma unroll
    for (int p = 0; p < 8; ++p)
#pragma unroll
      for (int j = 0; j < 8; ++j)
        uf[p][j] = U[(size_t)(p * 32 + quad * 8 + j) * Rn + ucol];
    f32x4 acc = {0.f, 0.f, 0.f, 0.f};
    const bf16_t* arow = wbuf + ln * 1032 + quad * 8;
#pragma unroll
    for (int kb = 0; kb < 32; ++kb) {
      bf16x8 bb;
#pragma unroll
      for (int j = 0; j < 8; ++j) bb[j] = (bf16_t)uf[kb & 7][j];
      const bf16x8 a = *(const bf16x8*)(arow + kb * 32);
      acc = MFMA_BF16(a, bb, acc);
      if (kb < 24) {
#pragma unroll
        for (int j = 0; j < 8; ++j)
          uf[kb & 7][j] = U[(size_t)((kb + 8) * 32 + quad * 8 + j) * Rn + ucol];
      }
    }
    // lane holds WU[rw][c], rw = m*16+quad*4+r, c = wv*16+ln; scatter to packed slots
#pragma unroll
    for (int r = 0; r < 4; ++r) {
      int rw = m * 16 + quad * 4 + r;
      int kb = rw >> 5;
      int sub = (rw >> 3) & 3;
      int j = rw & 7;
      size_t slot = ((size_t)(wv * 8 + kb) * 64 + sub * 16 + ln) * 8 + j;
      WUpk[slot] = (bf16_t)acc[r];
    }
  }
}

// ---- Fused integrator, R-space loop ----
//   hv_{h+1} = hv_h + hdt*(FU - T_h@WU),  FU = f@U, WU = W@U
//   v_out = v0 + s*dt*f - hdt*(S1@W),     S1 = sum T_h
//   x_out = x0 + s*dt*v0 + s^2*dt*hdt*f - dt*hdt*(S2@W),  S2 = sum c_h*T_h, c_h = s-ceil(h/2)
// U streamed once (init), W streamed once (final); loop is LDS+register only.
// This round: vectorized in/out via swizzled LDS restage (full-line HBM traffic),
// double-buffered T (1 barrier/half-step), dual MFMA chains.
__global__ __launch_bounds__(1024)
__attribute__((amdgpu_waves_per_eu(4, 4)))
void integrate_kernel(const float* __restrict__ x_in, const float* __restrict__ v_in,
                      const float* __restrict__ force,
                      const bf16_t* __restrict__ Upk, const bf16_t* __restrict__ Wpk,
                      const bf16_t* __restrict__ WUpk,
                      const int* __restrict__ steps_p, float* __restrict__ out) {
  // union: restage fsb[8][1024] f32 (32KB) / init abuf[3][16][520] bf16 (49920B)
  //        / loop tbf[2][16][264] bf16 / final sbuf[2][16][264] bf16
  __shared__ __align__(16) char smem[49920];
  bf16_t* abuf = (bf16_t*)smem;
  float* fsb = (float*)smem;

  const int tid = (int)threadIdx.x;
  const int wv = tid >> 6;  // 0..15
  const int l = tid & 63;
  const int ln = l & 15;
  const int quad = l >> 4;
  const int s = steps_p[0];
  const int nhalf = 2 * s;
  const int row_base = (int)blockIdx.x * BT;

  float* out_x = out;
  float* out_v = out + (size_t)Bn * Dn;

  // restage addressing: thread covers floats [tid*8, tid*8+8) of an 8x1024 chunk
  const int frow = tid >> 7;            // chunk row 0..7
  const int fr = (tid & 127) * 8;       // col0 within row
  const int sc0 = swz(fr);
  const int sc1 = sc0 ^ 4;
  int csw[4];
#pragma unroll
  for (int i = 0; i < 4; ++i) csw[i] = swz((wv * 4 + i) * 16 + ln);

  float xs[4][4], vs[4][4];  // ORIGINAL x0, v0 (C/D layout)
  bf16x2 fs2[4][2];

  // ---- vectorized input load: 6 chunks of 8 rows through swizzled LDS ----
  auto load_chunk = [&](const float* __restrict__ srcA, int HF, auto sink) {
    const float* src_ = srcA + (size_t)(row_base + HF * 8) * Dn;
    f32x4 a_ = *(const f32x4*)(src_ + tid * 8);
    f32x4 b_ = *(const f32x4*)(src_ + tid * 8 + 4);
    *(f32x4*)(fsb + frow * 1024 + sc0) = a_;
    *(f32x4*)(fsb + frow * 1024 + sc1) = b_;
    __syncthreads();
    if ((quad >> 1) == HF) {
#pragma unroll
      for (int i = 0; i < 4; ++i)
#pragma unroll
        for (int r = 0; r < 4; ++r)
          sink(i, r, fsb[((quad & 1) * 4 + r) * 1024 + csw[i]]);
    }
    __syncthreads();
  };
  load_chunk(x_in, 0, [&](int i, int r, float v_) { xs[i][r] = v_; });
  load_chunk(x_in, 1, [&](int i, int r, float v_) { xs[i][r] = v_; });
  load_chunk(v_in, 0, [&](int i, int r, float v_) { vs[i][r] = v_; });
  load_chunk(v_in, 1, [&](int i, int r, float v_) { vs[i][r] = v_; });
  load_chunk(force, 0, [&](int i, int r, float v_) { fs2[i][r >> 1][r & 1] = (bf16_t)v_; });
  load_chunk(force, 1, [&](int i, int r, float v_) { fs2[i][r >> 1][r & 1] = (bf16_t)v_; });

  // ---- init: hx0 = x0@U, hv0 = v0@U, FU = f@U; one Upk pass in two K-halves ----
  f32x4 hx = {0.f, 0.f, 0.f, 0.f};
  f32x4 hv = {0.f, 0.f, 0.f, 0.f};
  f32x4 FU = {0.f, 0.f, 0.f, 0.f};
#pragma unroll
  for (int kh = 0; kh < 2; ++kh) {
    if ((wv >> 3) == kh) {  // waves 0-7 stage K-cols [0,512); 8-15 stage [512,1024)
#pragma unroll
      for (int i = 0; i < 4; ++i) {
        const int col = (wv * 4 + i) * 16 + ln - kh * 512;
#pragma unroll
        for (int r = 0; r < 4; ++r) {
          const int ro = (quad * 4 + r) * 520 + col;
          abuf[ro] = (bf16_t)xs[i][r];
          abuf[8320 + ro] = (bf16_t)vs[i][r];
          abuf[16640 + ro] = fs2[i][r >> 1][r & 1];
        }
      }
    }
    __syncthreads();
    const bf16x8* up = (const bf16x8*)Upk + ((size_t)wv * 32 + kh * 16) * 64 + l;
    const bf16_t* ax = abuf + ln * 520 + quad * 8;
    bf16x8 ur[8];
#pragma unroll
    for (int p = 0; p < 8; ++p) ur[p] = up[p * 64];
#pragma unroll
    for (int kb = 0; kb < 16; ++kb) {
      const bf16x8 b = ur[kb & 7];
      if (kb < 8) ur[kb & 7] = up[(kb + 8) * 64];
      const bf16x8 a0 = *(const bf16x8*)(ax + kb * 32);
      const bf16x8 a1 = *(const bf16x8*)(ax + 8320 + kb * 32);
      const bf16x8 a2 = *(const bf16x8*)(ax + 16640 + kb * 32);
      hx = MFMA_BF16(a0, b, hx);
      hv = MFMA_BF16(a1, b, hv);
      FU = MFMA_BF16(a2, b, FU);
    }
    __syncthreads();
  }

  // ---- WU fragments (ct = wv), register-resident for the whole loop ----
  bf16x8 wu[8];
  {
    const bf16x8* wub = (const bf16x8*)WUpk + (size_t)wv * 8 * 64 + l;
#pragma unroll
    for (int kb = 0; kb < 8; ++kb) wu[kb] = wub[kb * 64];
  }

  // ---- R-space loop: zero global traffic; double-buffered T, 1 barrier/half-step ----
  f32x4 S1 = {0.f, 0.f, 0.f, 0.f};
  f32x4 S2 = {0.f, 0.f, 0.f, 0.f};
  bf16_t* tbase = (bf16_t*)smem;
  for (int h = 0; h < nhalf; ++h) {
    if (h & 1) {
#pragma unroll
      for (int r = 0; r < 4; ++r) hx[r] += DTv * hv[r];
    }
    const float ch = (float)(s - ((h + 1) >> 1));
    bf16_t* tb = tbase + (h & 1) * 4224;
#pragma unroll
    for (int r = 0; r < 4; ++r) {
      float a = fminf(fmaxf(hx[r], -15.f), 15.f);
      const float e = __expf(2.f * a);
      const float gate = (e - 1.f) / (e + 1.f);
      const float t = gate * hv[r] * hv[r];
      S1[r] += t;
      S2[r] += ch * t;
      tb[(quad * 4 + r) * 264 + wv * 16 + ln] = (bf16_t)t;
    }
    __syncthreads();
    f32x4 g0 = {0.f, 0.f, 0.f, 0.f};
    f32x4 g1 = {0.f, 0.f, 0.f, 0.f};
    const bf16_t* trow = tb + ln * 264 + quad * 8;
#pragma unroll
    for (int kb = 0; kb < 8; kb += 2) {
      g0 = MFMA_BF16(*(const bf16x8*)(trow + kb * 32), wu[kb], g0);
      g1 = MFMA_BF16(*(const bf16x8*)(trow + (kb + 1) * 32), wu[kb + 1], g1);
    }
#pragma unroll
    for (int r = 0; r < 4; ++r) hv[r] += HDT * (FU[r] - (g0[r] + g1[r]));
    // no second barrier: next iteration writes the OTHER buffer
  }
  __syncthreads();  // all reads of tbf done before sbuf overwrite

  // ---- final: G1 = S1@W, G2 = S2@W, one Wpk pass ----
  bf16_t* sbuf = (bf16_t*)smem;
#pragma unroll
  for (int r = 0; r < 4; ++r) {
    const int ro = (quad * 4 + r) * 264 + wv * 16 + ln;
    sbuf[ro] = (bf16_t)S1[r];
    sbuf[4224 + ro] = (bf16_t)S2[r];
  }
  __syncthreads();
  f32x4 ac1[4], ac2[4];
#pragma unroll
  for (int i = 0; i < 4; ++i) {
    ac1[i] = (f32x4){0.f, 0.f, 0.f, 0.f};
    ac2[i] = (f32x4){0.f, 0.f, 0.f, 0.f};
  }
  {
    const bf16x8* wp = (const bf16x8*)Wpk + (size_t)(wv * 4) * 8 * 64 + l;
    const bf16_t* s1row = sbuf + ln * 264 + quad * 8;
    const bf16_t* s2row = s1row + 4224;
    bf16x8 wr[4];
#pragma unroll
    for (int i = 0; i < 4; ++i) wr[i] = wp[i * 8 * 64];
#pragma unroll
    for (int kb = 0; kb < 8; ++kb) {
      const bf16x8 a1 = *(const bf16x8*)(s1row + kb * 32);
      const bf16x8 a2 = *(const bf16x8*)(s2row + kb * 32);
#pragma unroll
      for (int i = 0; i < 4; ++i) {
        const bf16x8 b = wr[i];
        if (kb < 7) wr[i] = wp[i * 8 * 64 + (kb + 1) * 64];
        ac1[i] = MFMA_BF16(a1, b, ac1[i]);
        ac2[i] = MFMA_BF16(a2, b, ac2[i]);
      }
    }
  }
  __syncthreads();  // sbuf reads done before fsb overwrite

  // ---- epilogue: closed form, full-line stores via swizzled LDS restage ----
  const float sf = (float)s;
  const float c_vf = sf * DTv;
  const float c_xf = sf * sf * DTv * HDT;
  auto store_chunk = [&](float* __restrict__ dstA, int HF, auto vex) {
    if ((quad >> 1) == HF) {
#pragma unroll
      for (int i = 0; i < 4; ++i)
#pragma unroll
        for (int r = 0; r < 4; ++r)
          fsb[((quad & 1) * 4 + r) * 1024 + csw[i]] = vex(i, r);
    }
    __syncthreads();
    float* dst_ = dstA + (size_t)(row_base + HF * 8) * Dn;
    *(f32x4*)(dst_ + tid * 8) = *(const f32x4*)(fsb + frow * 1024 + sc0);
    *(f32x4*)(dst_ + tid * 8 + 4) = *(const f32x4*)(fsb + frow * 1024 + sc1);
    __syncthreads();
  };
  auto vval = [&](int i, int r) {
    return vs[i][r] + c_vf * (float)fs2[i][r >> 1][r & 1] - HDT * ac1[i][r];
  };
  auto xval = [&](int i, int r) {
    return xs[i][r] + c_vf * vs[i][r] + c_xf * (float)fs2[i][r >> 1][r & 1] -
           DTv * HDT * ac2[i][r];
  };
  store_chunk(out_v, 0, vval);
  store_chunk(out_v, 1, vval);
  store_chunk(out_x, 0, xval);
  store_chunk(out_x, 1, xval);
}

extern "C" void kernel_launch(void* const* d_in, const int* in_sizes, int n_in,
                              void* d_out, int out_size, void* d_ws, size_t ws_size,
                              hipStream_t stream) {
  const float* x = (const float*)d_in[0];
  const float* v = (const float*)d_in[1];
  const float* force = (const float*)d_in[2];
  const float* U = (const float*)d_in[3];
  const float* W = (const float*)d_in[4];
  const int* steps = (const int*)d_in[5];

  bf16_t* Upk = (bf16_t*)d_ws;                          // 512 KB
  bf16_t* Wpk = (bf16_t*)((char*)d_ws + 512 * 1024);    // 512 KB
  bf16_t* WUpk = (bf16_t*)((char*)d_ws + 1024 * 1024);  // 128 KB

  setup_kernel<<<80, 1024, 0, stream>>>(U, W, Upk, Wpk, WUpk);
  integrate_kernel<<<Bn / BT, 1024, 0, stream>>>(x, v, force, Upk, Wpk, WUpk, steps,
                                                 (float*)d_out);
}